// Round 11
// baseline (148.646 us; speedup 1.0000x reference)
//
#include <hip/hip_runtime.h>
#include <stdint.h>

// Problem constants
#define N_TOK 16384
#define FEAT  256
#define EMB   128
#define NQ    13   // 12 sinc-quadrature nodes (t_q=e^{-10.8+0.9q}) + 1 analytic t=0 tail

typedef float  f32x4  __attribute__((ext_vector_type(4)));
typedef __bf16 bf16x8 __attribute__((ext_vector_type(8)));
typedef short  s16x8  __attribute__((ext_vector_type(8)));
typedef unsigned int u32x4 __attribute__((ext_vector_type(4)));

__device__ __forceinline__ unsigned short bf16_rne(float f) {
    union { float f; unsigned u; } v; v.f = f;
    unsigned u = v.u;
    return (unsigned short)((u + 0x7FFFu + ((u >> 16) & 1u)) >> 16);
}
__device__ __forceinline__ float bf16_to_f32(unsigned short s) {
    union { unsigned u; float f; } v; v.u = ((unsigned)s) << 16; return v.f;
}
// pack two f32 into (bf16(a) | bf16(b)<<16) by TRUNCATION (a -> low half).
// ~3.5 VALU/el vs ~6 for RNE; bias ~2^-9 relative -- absmax margin is 4x.
__device__ __forceinline__ unsigned pack_trunc(float a, float b) {
    union { float f; unsigned u; } ua, ub; ua.f = a; ub.f = b;
    return (ub.u & 0xFFFF0000u) | (ua.u >> 16);
}
__device__ __forceinline__ void async_cp16(const void* g, void* l) {
    __builtin_amdgcn_global_load_lds(
        (const __attribute__((address_space(1))) unsigned int*)g,
        (__attribute__((address_space(3))) unsigned int*)l, 16, 0, 0);
}

// ---------------- k0: W1 -> W1T bf16 [128][256]; W2 -> W2T bf16 [128][128]
__global__ void k0_transpose(const float* __restrict__ W1, const float* __restrict__ W2,
                             unsigned short* __restrict__ W1T, unsigned short* __restrict__ W2T)
{
    const int tid  = blockIdx.x * blockDim.x + threadIdx.x;
    const int nthr = gridDim.x * blockDim.x;
    for (int i = tid; i < FEAT * EMB; i += nthr) {
        const int r = i >> 7, c = i & 127;
        W1T[c * FEAT + r] = bf16_rne(W1[i]);
    }
    for (int i = tid; i < EMB * EMB; i += nthr) {
        const int r = i >> 7, c = i & 127;
        W2T[c * EMB + r] = bf16_rne(W2[i]);
    }
}

// ---------------- k1: h = x@W1 + b1 ; emit h bf16, hT bf16, and (fused k1b) UT[q][i]
// W1T staged in LDS once; x prefetched to regs; UT written from the butterfly-reduced
// row norm (all 16 lanes hold v -> lane l15==q writes its q-plane, 1 exp/lane).
__global__ __launch_bounds__(256) void k1_proj(
    const float* __restrict__ x, const unsigned short* __restrict__ W1T,
    const float* __restrict__ b1,
    unsigned short* __restrict__ h, unsigned short* __restrict__ hT,
    float* __restrict__ UT)
{
    __shared__ __align__(16) unsigned char W1s[65536];   // 128 rows x 512 B, blk b' = b ^ (row&15)
    __shared__ unsigned short ldsT[128 * 68];
    const int lane = threadIdx.x & 63;
    const int wave = threadIdx.x >> 6;
    const int quad = lane >> 4;
    const int l15  = lane & 15;
    const int arow = blockIdx.x * 64 + wave * 16 + l15;

    float4 xv[16];
    #pragma unroll
    for (int ks = 0; ks < 8; ++ks) {
        const float* xp = x + (size_t)arow * FEAT + ks * 32 + quad * 8;
        xv[2 * ks]     = *(const float4*)xp;
        xv[2 * ks + 1] = *(const float4*)(xp + 4);
    }
    #pragma unroll
    for (int c = 0; c < 16; ++c) {
        const int chunk = wave * 16 + c;
        const int row = chunk * 2 + (lane >> 5);
        const int b = (lane & 31) ^ (row & 15);
        async_cp16(W1T + (size_t)row * FEAT + b * 8, W1s + chunk * 1024);
    }
    bf16x8 afr[8];
    #pragma unroll
    for (int ks = 0; ks < 8; ++ks) {
        const float4 xa = xv[2 * ks], xb = xv[2 * ks + 1];
        s16x8 at;
        at[0] = (short)bf16_rne(xa.x); at[1] = (short)bf16_rne(xa.y);
        at[2] = (short)bf16_rne(xa.z); at[3] = (short)bf16_rne(xa.w);
        at[4] = (short)bf16_rne(xb.x); at[5] = (short)bf16_rne(xb.y);
        at[6] = (short)bf16_rne(xb.z); at[7] = (short)bf16_rne(xb.w);
        afr[ks] = __builtin_bit_cast(bf16x8, at);
    }
    __syncthreads();   // W1s staged (vmcnt drain)

    const f32x4 zero4 = {0.f, 0.f, 0.f, 0.f};
    f32x4 acc[8];
    #pragma unroll
    for (int n0 = 0; n0 < 8; ++n0) acc[n0] = zero4;
    #pragma unroll
    for (int ks = 0; ks < 8; ++ks)
        #pragma unroll
        for (int n0 = 0; n0 < 8; ++n0) {
            const int n = n0 * 16 + l15;
            const int b = (ks * 4 + quad) ^ (n & 15);
            const bf16x8 bfr = *(const bf16x8*)(W1s + n * 512 + b * 16);
            acc[n0] = __builtin_amdgcn_mfma_f32_16x16x32_bf16(afr[ks], bfr, acc[n0], 0, 0, 0);
        }

    const int rbase = blockIdx.x * 64 + wave * 16 + quad * 4;
    float dpart[4] = {0.f, 0.f, 0.f, 0.f};
    #pragma unroll
    for (int n0 = 0; n0 < 8; ++n0) {
        const int col = n0 * 16 + l15;
        const float bias = b1[col];
        unsigned short hb[4];
        #pragma unroll
        for (int r = 0; r < 4; ++r) {
            const float hv = acc[n0][r] + bias;
            const unsigned short q = bf16_rne(hv);
            hb[r] = q;
            const float bb = bf16_to_f32(q);
            dpart[r] += bb * bb;
            h[(size_t)(rbase + r) * EMB + col] = q;
        }
        ushort4 pk = make_ushort4(hb[0], hb[1], hb[2], hb[3]);
        *(ushort4*)&ldsT[col * 68 + wave * 16 + quad * 4] = pk;
    }
    const float tql = __expf(0.9f * (float)l15 - 10.8f);   // lane's quadrature node
    #pragma unroll
    for (int r = 0; r < 4; ++r) {
        float v = dpart[r];
        v += __shfl_xor(v, 1);
        v += __shfl_xor(v, 2);
        v += __shfl_xor(v, 4);
        v += __shfl_xor(v, 8);
        // fused k1b: UT[q][row], lane l15 == q
        if (l15 < 12)       UT[(size_t)l15 * N_TOK + rbase + r] = __expf(-tql * v);
        else if (l15 == 12) UT[(size_t)12  * N_TOK + rbase + r] = 1.0f;
    }
    __syncthreads();
    const int rbase0 = blockIdx.x * 64;
    #pragma unroll
    for (int i = 0; i < 4; ++i) {
        const int slot = i * 256 + threadIdx.x;
        const int c    = slot >> 3;
        const int seg  = slot & 7;
        const ushort4 a0 = *(const ushort4*)&ldsT[c * 68 + seg * 8];
        const ushort4 a1 = *(const ushort4*)&ldsT[c * 68 + seg * 8 + 4];
        ushort4 o[2] = {a0, a1};
        *(uint4*)&hT[(size_t)c * N_TOK + rbase0 + seg * 8] = *(const uint4*)o;
    }
}

// ---------------- k2a: Gram partials G_q = h^T diag(u^q) h, K split 64 x 256.
// R11: grid 832 (3.25 blocks/CU; was 416 = 1.6 -- grid-starved) at launch_bounds(256,3)
// (64 AGPR + ~70 VGPR ~= 134 < 170: safe; (256,4)=128 budget risks the R2/R6 spill).
// u-scale via pack_trunc (-45% VALU vs RNE).
__global__ __launch_bounds__(256, 3) void k2a_gram(
    const unsigned short* __restrict__ hT, const float* __restrict__ UT,
    float* __restrict__ Gp)
{
    __shared__ __align__(16) unsigned char Rb[32768];   // 128 rows x 256 B (128-token window)
    const int lane = threadIdx.x & 63;
    const int wave = threadIdx.x >> 6;
    const int quad = lane >> 4;
    const int l15  = lane & 15;
    const int q  = blockIdx.x >> 6;     // 0..12
    const int kc = blockIdx.x & 63;     // K-chunk (256 tokens)
    const int E = wave & 1, F = wave >> 1;

    const f32x4 zero4 = {0.f, 0.f, 0.f, 0.f};
    f32x4 acc[4][4];
    #pragma unroll
    for (int mt = 0; mt < 4; ++mt)
        #pragma unroll
        for (int nt = 0; nt < 4; ++nt) acc[mt][nt] = zero4;

    #pragma unroll 1
    for (int sub = 0; sub < 2; ++sub) {
        const int kwin = kc * 256 + sub * 128;
        __syncthreads();   // prev sub's LDS reads done
        #pragma unroll
        for (int c = 0; c < 8; ++c) {
            const int chunk = wave * 8 + c;
            const int row = chunk * 4 + (lane >> 4);
            const int b = (lane & 15) ^ (row & 15);
            async_cp16(hT + (size_t)row * N_TOK + kwin + b * 8, Rb + chunk * 1024);
        }
        __syncthreads();   // staged data visible

        #pragma unroll
        for (int ks = 0; ks < 4; ++ks) {
            const int kb = kwin + ks * 32 + quad * 8;
            const float4 ua = *(const float4*)(UT + (size_t)q * N_TOK + kb);
            const float4 ub = *(const float4*)(UT + (size_t)q * N_TOK + kb + 4);
            const float uv[8] = {ua.x, ua.y, ua.z, ua.w, ub.x, ub.y, ub.z, ub.w};
            bf16x8 au[4];
            #pragma unroll
            for (int mt = 0; mt < 4; ++mt) {
                const int re = E * 64 + mt * 16 + l15;
                const int b = (ks * 4 + quad) ^ (re & 15);
                const s16x8 raw = *(const s16x8*)(Rb + re * 256 + b * 16);
                u32x4 ww;
                #pragma unroll
                for (int w = 0; w < 4; ++w) {
                    const float fa = bf16_to_f32((unsigned short)raw[2 * w])     * uv[2 * w];
                    const float fb = bf16_to_f32((unsigned short)raw[2 * w + 1]) * uv[2 * w + 1];
                    ww[w] = pack_trunc(fa, fb);
                }
                au[mt] = __builtin_bit_cast(bf16x8, ww);
            }
            #pragma unroll
            for (int nt = 0; nt < 4; ++nt) {
                const int rf = F * 64 + nt * 16 + l15;
                const int b = (ks * 4 + quad) ^ (rf & 15);
                const bf16x8 bfr = *(const bf16x8*)(Rb + rf * 256 + b * 16);
                #pragma unroll
                for (int mt = 0; mt < 4; ++mt)
                    acc[mt][nt] = __builtin_amdgcn_mfma_f32_16x16x32_bf16(au[mt], bfr, acc[mt][nt], 0, 0, 0);
            }
        }
    }

    float* gp = Gp + (size_t)(q * 64 + kc) * (EMB * EMB);
    #pragma unroll
    for (int mt = 0; mt < 4; ++mt)
        #pragma unroll
        for (int nt = 0; nt < 4; ++nt)
            #pragma unroll
            for (int r = 0; r < 4; ++r)
                gp[(size_t)(E * 64 + mt * 16 + quad * 4 + r) * EMB + F * 64 + nt * 16 + l15] = acc[mt][nt][r];
}

// ---------------- k2r: reduce 64 K-chunk partials -> G (fp32). Pure streaming.
__global__ __launch_bounds__(256) void k2r_reduce(const float* __restrict__ Gp, float* __restrict__ G)
{
    const int q   = blockIdx.x >> 6;                       // 13
    const int idx = (blockIdx.x & 63) * 256 + threadIdx.x; // 0..16383
    float s = 0.f;
    #pragma unroll 8
    for (int kc = 0; kc < 64; ++kc)
        s += Gp[(size_t)(q * 64 + kc) * (EMB * EMB) + idx];
    G[(size_t)q * (EMB * EMB) + idx] = s;
}

// ---------------- k2b: GWT[q][o][f] = (2 w_q) * (W2^T G_q)[o][f], bf16.
__global__ __launch_bounds__(256) void k2b_gwt(
    const float* __restrict__ G, const unsigned short* __restrict__ W2T,
    unsigned short* __restrict__ GWT)
{
    const int q  = blockIdx.x >> 3;     // 0..12
    const int fs = blockIdx.x & 7;      // f-subtile (16 rows)
    const int lane = threadIdx.x & 63;
    const int wave = threadIdx.x >> 6;
    const int quad = lane >> 4;
    const int l15  = lane & 15;
    const float scale = (q == 12) ? 2.0f * __expf(-10.8f)
                                  : 1.8f * __expf(0.9f * (float)q - 10.8f);  // 2*w_q
    const int fg = fs * 16 + l15;

    const f32x4 zero4 = {0.f, 0.f, 0.f, 0.f};
    f32x4 acc[2];
    acc[0] = zero4; acc[1] = zero4;
    #pragma unroll
    for (int ks = 0; ks < 4; ++ks) {
        const float* p = G + (size_t)q * (EMB * EMB) + (size_t)fg * EMB + ks * 32 + quad * 8;
        const float4 x1 = *(const float4*)p;
        const float4 x2 = *(const float4*)(p + 4);
        const float bv[8] = {x1.x, x1.y, x1.z, x1.w, x2.x, x2.y, x2.z, x2.w};
        s16x8 sb;
        #pragma unroll
        for (int j = 0; j < 8; ++j) sb[j] = (short)bf16_rne(bv[j]);
        const bf16x8 bfr = __builtin_bit_cast(bf16x8, sb);
        #pragma unroll
        for (int mt = 0; mt < 2; ++mt) {
            const int o = wave * 32 + mt * 16 + l15;
            const bf16x8 afr = *(const bf16x8*)(W2T + (size_t)o * EMB + ks * 32 + quad * 8);
            acc[mt] = __builtin_amdgcn_mfma_f32_16x16x32_bf16(afr, bfr, acc[mt], 0, 0, 0);
        }
    }
    #pragma unroll
    for (int mt = 0; mt < 2; ++mt)
        #pragma unroll
        for (int r = 0; r < 4; ++r)
            GWT[(size_t)q * (EMB * EMB) + (size_t)(wave * 32 + mt * 16 + quad * 4 + r) * EMB + fs * 16 + l15]
                = bf16_rne(acc[mt][r] * scale);
}

// ---------------- k2c: out[i][o] = relu(b2[o] + sum_q (u_i^q h_i) . GWT_q[o][:])
// u-scaled A-fragment (pack_trunc), double-buffered GWT staging (1 barrier/q).
__global__ __launch_bounds__(256) void k2c_apply(
    const unsigned short* __restrict__ h, const unsigned short* __restrict__ GWT,
    const float* __restrict__ UT, const float* __restrict__ b2,
    float* __restrict__ out)
{
    __shared__ __align__(16) unsigned char Gs[2][32768];
    const int lane = threadIdx.x & 63;
    const int wave = threadIdx.x >> 6;
    const int quad = lane >> 4;
    const int l15  = lane & 15;
    const int i0   = blockIdx.x * 64 + wave * 16;
    const int irow = i0 + l15;

    bf16x8 araw[4];
    #pragma unroll
    for (int ks = 0; ks < 4; ++ks)
        araw[ks] = *(const bf16x8*)(h + (size_t)irow * EMB + ks * 32 + quad * 8);

    const f32x4 zero4 = {0.f, 0.f, 0.f, 0.f};
    f32x4 acc[8];
    #pragma unroll
    for (int nt = 0; nt < 8; ++nt) acc[nt] = zero4;

    #pragma unroll
    for (int c = 0; c < 8; ++c) {
        const int chunk = wave * 8 + c;
        const int row = chunk * 4 + (lane >> 4);
        const int b = (lane & 15) ^ (row & 15);
        async_cp16(GWT + (size_t)row * EMB + b * 8, &Gs[0][chunk * 1024]);
    }
    #pragma unroll 1
    for (int q = 0; q < NQ; ++q) {
        __syncthreads();   // stage(q) complete + prev compute's reads done
        if (q + 1 < NQ) {
            const unsigned short* src = GWT + (size_t)(q + 1) * (EMB * EMB);
            unsigned char* dst = Gs[(q + 1) & 1];
            #pragma unroll
            for (int c = 0; c < 8; ++c) {
                const int chunk = wave * 8 + c;
                const int row = chunk * 4 + (lane >> 4);
                const int b = (lane & 15) ^ (row & 15);
                async_cp16(src + (size_t)row * EMB + b * 8, dst + chunk * 1024);
            }
        }
        const float u = UT[(size_t)q * N_TOK + irow];
        bf16x8 au[4];
        #pragma unroll
        for (int ks = 0; ks < 4; ++ks) {
            const s16x8 raw = __builtin_bit_cast(s16x8, araw[ks]);
            u32x4 ww;
            #pragma unroll
            for (int w = 0; w < 4; ++w) {
                const float fa = bf16_to_f32((unsigned short)raw[2 * w])     * u;
                const float fb = bf16_to_f32((unsigned short)raw[2 * w + 1]) * u;
                ww[w] = pack_trunc(fa, fb);
            }
            au[ks] = __builtin_bit_cast(bf16x8, ww);
        }
        const unsigned char* gb = Gs[q & 1];
        #pragma unroll
        for (int nt = 0; nt < 8; ++nt) {
            const int o = nt * 16 + l15;
            #pragma unroll
            for (int ks = 0; ks < 4; ++ks) {
                const int b = (ks * 4 + quad) ^ (o & 15);
                const bf16x8 bfr = *(const bf16x8*)(gb + o * 256 + b * 16);
                acc[nt] = __builtin_amdgcn_mfma_f32_16x16x32_bf16(au[ks], bfr, acc[nt], 0, 0, 0);
            }
        }
    }

    #pragma unroll
    for (int nt = 0; nt < 8; ++nt) {
        const float bias = b2[nt * 16 + l15];
        #pragma unroll
        for (int r = 0; r < 4; ++r) {
            const float v = acc[nt][r] + bias;
            out[(size_t)(i0 + quad * 4 + r) * EMB + nt * 16 + l15] = v > 0.f ? v : 0.f;
        }
    }
}

extern "C" void kernel_launch(void* const* d_in, const int* in_sizes, int n_in,
                              void* d_out, int out_size, void* d_ws, size_t ws_size,
                              hipStream_t stream) {
    const float* x  = (const float*)d_in[0];
    const float* W1 = (const float*)d_in[1];
    const float* b1 = (const float*)d_in[2];
    const float* W2 = (const float*)d_in[3];
    const float* b2 = (const float*)d_in[4];
    float* out = (float*)d_out;

    char* ws = (char*)d_ws;
    // ws (bytes): h 4MB | hT 4MB | W1T 64KB | W2T 32KB | UT 13xN f32 (832KB)
    // | Gp 13x64x64KB (54.5MB) | G 13x64KB (832KB) | GWT 13x32KB bf16 (416KB) ~= 65.1MB (<75.7 proven)
    unsigned short* h   = (unsigned short*)(ws);
    unsigned short* hT  = (unsigned short*)(ws + 4194304);
    unsigned short* W1T = (unsigned short*)(ws + 8388608);
    unsigned short* W2T = (unsigned short*)(ws + 8454144);
    float*          UT  = (float*)        (ws + 8486912);
    float*          Gp  = (float*)        (ws + 9338880);
    float*          G   = (float*)        (ws + 63864832);
    unsigned short* GWT = (unsigned short*)(ws + 64716800);

    k0_transpose<<<dim3(16),      dim3(256), 0, stream>>>(W1, W2, W1T, W2T);
    k1_proj     <<<dim3(256),     dim3(256), 0, stream>>>(x, W1T, b1, h, hT, UT);
    k2a_gram    <<<dim3(NQ * 64), dim3(256), 0, stream>>>(hT, UT, Gp);
    k2r_reduce  <<<dim3(NQ * 64), dim3(256), 0, stream>>>(Gp, G);
    k2b_gwt     <<<dim3(NQ * 8),  dim3(256), 0, stream>>>(G, W2T, GWT);
    k2c_apply   <<<dim3(256),     dim3(256), 0, stream>>>(h, GWT, UT, b2, out);
}

// Round 12
// 134.489 us; speedup vs baseline: 1.1053x; 1.1053x over previous
//
#include <hip/hip_runtime.h>
#include <stdint.h>

// Problem constants
#define N_TOK 16384
#define FEAT  256
#define EMB   128
#define NQ    13   // 12 sinc-quadrature nodes (t_q=e^{-10.8+0.9q}) + 1 analytic t=0 tail
#define KC    16   // K-chunks in k2a: 1024 tokens each. Partial traffic = NQ*KC*64KB = 13.3MB.

typedef float  f32x4  __attribute__((ext_vector_type(4)));
typedef __bf16 bf16x8 __attribute__((ext_vector_type(8)));
typedef short  s16x8  __attribute__((ext_vector_type(8)));
typedef unsigned int u32x4 __attribute__((ext_vector_type(4)));

__device__ __forceinline__ unsigned short bf16_rne(float f) {
    union { float f; unsigned u; } v; v.f = f;
    unsigned u = v.u;
    return (unsigned short)((u + 0x7FFFu + ((u >> 16) & 1u)) >> 16);
}
__device__ __forceinline__ float bf16_to_f32(unsigned short s) {
    union { unsigned u; float f; } v; v.u = ((unsigned)s) << 16; return v.f;
}
// pack two f32 -> (bf16(a) | bf16(b)<<16) by truncation; bias ~2^-9 rel (absmax margin 2.6x)
__device__ __forceinline__ unsigned pack_trunc(float a, float b) {
    union { float f; unsigned u; } ua, ub; ua.f = a; ub.f = b;
    return (ub.u & 0xFFFF0000u) | (ua.u >> 16);
}
__device__ __forceinline__ void async_cp16(const void* g, void* l) {
    __builtin_amdgcn_global_load_lds(
        (const __attribute__((address_space(1))) unsigned int*)g,
        (__attribute__((address_space(3))) unsigned int*)l, 16, 0, 0);
}

// ---------------- k0: W1 -> W1T bf16 [128][256]; W2 -> W2T bf16 [128][128]
__global__ void k0_transpose(const float* __restrict__ W1, const float* __restrict__ W2,
                             unsigned short* __restrict__ W1T, unsigned short* __restrict__ W2T)
{
    const int tid  = blockIdx.x * blockDim.x + threadIdx.x;
    const int nthr = gridDim.x * blockDim.x;
    for (int i = tid; i < FEAT * EMB; i += nthr) {
        const int r = i >> 7, c = i & 127;
        W1T[c * FEAT + r] = bf16_rne(W1[i]);
    }
    for (int i = tid; i < EMB * EMB; i += nthr) {
        const int r = i >> 7, c = i & 127;
        W2T[c * EMB + r] = bf16_rne(W2[i]);
    }
}

// ---------------- k1: h = x@W1 + b1 ; emit h bf16, hT bf16, UT[q][i] (fused)
__global__ __launch_bounds__(256) void k1_proj(
    const float* __restrict__ x, const unsigned short* __restrict__ W1T,
    const float* __restrict__ b1,
    unsigned short* __restrict__ h, unsigned short* __restrict__ hT,
    float* __restrict__ UT)
{
    __shared__ __align__(16) unsigned char W1s[65536];   // 128 rows x 512 B, blk b' = b ^ (row&15)
    __shared__ unsigned short ldsT[128 * 68];
    const int lane = threadIdx.x & 63;
    const int wave = threadIdx.x >> 6;
    const int quad = lane >> 4;
    const int l15  = lane & 15;
    const int arow = blockIdx.x * 64 + wave * 16 + l15;

    float4 xv[16];
    #pragma unroll
    for (int ks = 0; ks < 8; ++ks) {
        const float* xp = x + (size_t)arow * FEAT + ks * 32 + quad * 8;
        xv[2 * ks]     = *(const float4*)xp;
        xv[2 * ks + 1] = *(const float4*)(xp + 4);
    }
    #pragma unroll
    for (int c = 0; c < 16; ++c) {
        const int chunk = wave * 16 + c;
        const int row = chunk * 2 + (lane >> 5);
        const int b = (lane & 31) ^ (row & 15);
        async_cp16(W1T + (size_t)row * FEAT + b * 8, W1s + chunk * 1024);
    }
    bf16x8 afr[8];
    #pragma unroll
    for (int ks = 0; ks < 8; ++ks) {
        const float4 xa = xv[2 * ks], xb = xv[2 * ks + 1];
        s16x8 at;
        at[0] = (short)bf16_rne(xa.x); at[1] = (short)bf16_rne(xa.y);
        at[2] = (short)bf16_rne(xa.z); at[3] = (short)bf16_rne(xa.w);
        at[4] = (short)bf16_rne(xb.x); at[5] = (short)bf16_rne(xb.y);
        at[6] = (short)bf16_rne(xb.z); at[7] = (short)bf16_rne(xb.w);
        afr[ks] = __builtin_bit_cast(bf16x8, at);
    }
    __syncthreads();   // W1s staged (vmcnt drain)

    const f32x4 zero4 = {0.f, 0.f, 0.f, 0.f};
    f32x4 acc[8];
    #pragma unroll
    for (int n0 = 0; n0 < 8; ++n0) acc[n0] = zero4;
    #pragma unroll
    for (int ks = 0; ks < 8; ++ks)
        #pragma unroll
        for (int n0 = 0; n0 < 8; ++n0) {
            const int n = n0 * 16 + l15;
            const int b = (ks * 4 + quad) ^ (n & 15);
            const bf16x8 bfr = *(const bf16x8*)(W1s + n * 512 + b * 16);
            acc[n0] = __builtin_amdgcn_mfma_f32_16x16x32_bf16(afr[ks], bfr, acc[n0], 0, 0, 0);
        }

    const int rbase = blockIdx.x * 64 + wave * 16 + quad * 4;
    float dpart[4] = {0.f, 0.f, 0.f, 0.f};
    #pragma unroll
    for (int n0 = 0; n0 < 8; ++n0) {
        const int col = n0 * 16 + l15;
        const float bias = b1[col];
        unsigned short hb[4];
        #pragma unroll
        for (int r = 0; r < 4; ++r) {
            const float hv = acc[n0][r] + bias;
            const unsigned short q = bf16_rne(hv);
            hb[r] = q;
            const float bb = bf16_to_f32(q);
            dpart[r] += bb * bb;
            h[(size_t)(rbase + r) * EMB + col] = q;
        }
        ushort4 pk = make_ushort4(hb[0], hb[1], hb[2], hb[3]);
        *(ushort4*)&ldsT[col * 68 + wave * 16 + quad * 4] = pk;
    }
    const float tql = __expf(0.9f * (float)l15 - 10.8f);   // lane's quadrature node
    #pragma unroll
    for (int r = 0; r < 4; ++r) {
        float v = dpart[r];
        v += __shfl_xor(v, 1);
        v += __shfl_xor(v, 2);
        v += __shfl_xor(v, 4);
        v += __shfl_xor(v, 8);
        if (l15 < 12)       UT[(size_t)l15 * N_TOK + rbase + r] = __expf(-tql * v);
        else if (l15 == 12) UT[(size_t)12  * N_TOK + rbase + r] = 1.0f;
    }
    __syncthreads();
    const int rbase0 = blockIdx.x * 64;
    #pragma unroll
    for (int i = 0; i < 4; ++i) {
        const int slot = i * 256 + threadIdx.x;
        const int c    = slot >> 3;
        const int seg  = slot & 7;
        const ushort4 a0 = *(const ushort4*)&ldsT[c * 68 + seg * 8];
        const ushort4 a1 = *(const ushort4*)&ldsT[c * 68 + seg * 8 + 4];
        ushort4 o[2] = {a0, a1};
        *(uint4*)&hT[(size_t)c * N_TOK + rbase0 + seg * 8] = *(const uint4*)o;
    }
}

// ---------------- k2a: Gram partials G_q = h^T diag(u^q) h, K split 16 x 1024.
// R12: KC=16 (was 64 -- R11's doubled partial slab cost ~+9us round-trip). Grid 208,
// fat blocks (8 sub-windows of 128 tokens); partial writes 13.3 MB total.
__global__ __launch_bounds__(256, 3) void k2a_gram(
    const unsigned short* __restrict__ hT, const float* __restrict__ UT,
    float* __restrict__ Gp)
{
    __shared__ __align__(16) unsigned char Rb[32768];   // 128 rows x 256 B (128-token window)
    const int lane = threadIdx.x & 63;
    const int wave = threadIdx.x >> 6;
    const int quad = lane >> 4;
    const int l15  = lane & 15;
    const int q  = blockIdx.x >> 4;     // 0..12
    const int kc = blockIdx.x & 15;     // K-chunk (1024 tokens)
    const int E = wave & 1, F = wave >> 1;

    const f32x4 zero4 = {0.f, 0.f, 0.f, 0.f};
    f32x4 acc[4][4];
    #pragma unroll
    for (int mt = 0; mt < 4; ++mt)
        #pragma unroll
        for (int nt = 0; nt < 4; ++nt) acc[mt][nt] = zero4;

    #pragma unroll 1
    for (int sub = 0; sub < 8; ++sub) {
        const int kwin = kc * 1024 + sub * 128;
        __syncthreads();   // prev sub's LDS reads done
        #pragma unroll
        for (int c = 0; c < 8; ++c) {
            const int chunk = wave * 8 + c;
            const int row = chunk * 4 + (lane >> 4);
            const int b = (lane & 15) ^ (row & 15);
            async_cp16(hT + (size_t)row * N_TOK + kwin + b * 8, Rb + chunk * 1024);
        }
        __syncthreads();   // staged data visible

        #pragma unroll
        for (int ks = 0; ks < 4; ++ks) {
            const int kb = kwin + ks * 32 + quad * 8;
            const float4 ua = *(const float4*)(UT + (size_t)q * N_TOK + kb);
            const float4 ub = *(const float4*)(UT + (size_t)q * N_TOK + kb + 4);
            const float uv[8] = {ua.x, ua.y, ua.z, ua.w, ub.x, ub.y, ub.z, ub.w};
            bf16x8 au[4];
            #pragma unroll
            for (int mt = 0; mt < 4; ++mt) {
                const int re = E * 64 + mt * 16 + l15;
                const int b = (ks * 4 + quad) ^ (re & 15);
                const s16x8 raw = *(const s16x8*)(Rb + re * 256 + b * 16);
                u32x4 ww;
                #pragma unroll
                for (int w = 0; w < 4; ++w) {
                    const float fa = bf16_to_f32((unsigned short)raw[2 * w])     * uv[2 * w];
                    const float fb = bf16_to_f32((unsigned short)raw[2 * w + 1]) * uv[2 * w + 1];
                    ww[w] = pack_trunc(fa, fb);
                }
                au[mt] = __builtin_bit_cast(bf16x8, ww);
            }
            #pragma unroll
            for (int nt = 0; nt < 4; ++nt) {
                const int rf = F * 64 + nt * 16 + l15;
                const int b = (ks * 4 + quad) ^ (rf & 15);
                const bf16x8 bfr = *(const bf16x8*)(Rb + rf * 256 + b * 16);
                #pragma unroll
                for (int mt = 0; mt < 4; ++mt)
                    acc[mt][nt] = __builtin_amdgcn_mfma_f32_16x16x32_bf16(au[mt], bfr, acc[mt][nt], 0, 0, 0);
            }
        }
    }

    float* gp = Gp + (size_t)(q * KC + kc) * (EMB * EMB);
    #pragma unroll
    for (int mt = 0; mt < 4; ++mt)
        #pragma unroll
        for (int nt = 0; nt < 4; ++nt)
            #pragma unroll
            for (int r = 0; r < 4; ++r)
                gp[(size_t)(E * 64 + mt * 16 + quad * 4 + r) * EMB + F * 64 + nt * 16 + l15] = acc[mt][nt][r];
}

// ---------------- k2r: reduce KC partials -> G (fp32). Streaming, 13.3 MB read.
__global__ __launch_bounds__(256) void k2r_reduce(const float* __restrict__ Gp, float* __restrict__ G)
{
    const int q   = blockIdx.x >> 6;                       // 13
    const int idx = (blockIdx.x & 63) * 256 + threadIdx.x; // 0..16383
    float s = 0.f;
    #pragma unroll
    for (int kc = 0; kc < KC; ++kc)
        s += Gp[(size_t)(q * KC + kc) * (EMB * EMB) + idx];
    G[(size_t)q * (EMB * EMB) + idx] = s;
}

// ---------------- k2b: GWT[q][o][f] = (2 w_q) * (W2^T G_q)[o][f], bf16.
__global__ __launch_bounds__(256) void k2b_gwt(
    const float* __restrict__ G, const unsigned short* __restrict__ W2T,
    unsigned short* __restrict__ GWT)
{
    const int q  = blockIdx.x >> 3;     // 0..12
    const int fs = blockIdx.x & 7;      // f-subtile (16 rows)
    const int lane = threadIdx.x & 63;
    const int wave = threadIdx.x >> 6;
    const int quad = lane >> 4;
    const int l15  = lane & 15;
    const float scale = (q == 12) ? 2.0f * __expf(-10.8f)
                                  : 1.8f * __expf(0.9f * (float)q - 10.8f);  // 2*w_q
    const int fg = fs * 16 + l15;

    const f32x4 zero4 = {0.f, 0.f, 0.f, 0.f};
    f32x4 acc[2];
    acc[0] = zero4; acc[1] = zero4;
    #pragma unroll
    for (int ks = 0; ks < 4; ++ks) {
        const float* p = G + (size_t)q * (EMB * EMB) + (size_t)fg * EMB + ks * 32 + quad * 8;
        const float4 x1 = *(const float4*)p;
        const float4 x2 = *(const float4*)(p + 4);
        const float bv[8] = {x1.x, x1.y, x1.z, x1.w, x2.x, x2.y, x2.z, x2.w};
        s16x8 sb;
        #pragma unroll
        for (int j = 0; j < 8; ++j) sb[j] = (short)bf16_rne(bv[j]);
        const bf16x8 bfr = __builtin_bit_cast(bf16x8, sb);
        #pragma unroll
        for (int mt = 0; mt < 2; ++mt) {
            const int o = wave * 32 + mt * 16 + l15;
            const bf16x8 afr = *(const bf16x8*)(W2T + (size_t)o * EMB + ks * 32 + quad * 8);
            acc[mt] = __builtin_amdgcn_mfma_f32_16x16x32_bf16(afr, bfr, acc[mt], 0, 0, 0);
        }
    }
    #pragma unroll
    for (int mt = 0; mt < 2; ++mt)
        #pragma unroll
        for (int r = 0; r < 4; ++r)
            GWT[(size_t)q * (EMB * EMB) + (size_t)(wave * 32 + mt * 16 + quad * 4 + r) * EMB + fs * 16 + l15]
                = bf16_rne(acc[mt][r] * scale);
}

// ---------------- k2c: out[i][o] = relu(b2[o] + sum_q (u_i^q h_i) . GWT_q[o][:])
// R12: 512 blocks of 32 i-rows (wave = 16i x 64o quarter, acc 16 AGPR) -> 2 blocks/CU;
// the 13 serial barrier phases now overlap across co-resident blocks (was 1/CU = exposed).
__global__ __launch_bounds__(256, 2) void k2c_apply(
    const unsigned short* __restrict__ h, const unsigned short* __restrict__ GWT,
    const float* __restrict__ UT, const float* __restrict__ b2,
    float* __restrict__ out)
{
    __shared__ __align__(16) unsigned char Gs[2][32768];
    const int lane = threadIdx.x & 63;
    const int wave = threadIdx.x >> 6;
    const int quad = lane >> 4;
    const int l15  = lane & 15;
    const int i0   = blockIdx.x * 32 + (wave & 1) * 16;   // wave's 16 i-rows
    const int F    = wave >> 1;                           // wave's o-half (64 cols)
    const int irow = i0 + l15;

    bf16x8 araw[4];
    #pragma unroll
    for (int ks = 0; ks < 4; ++ks)
        araw[ks] = *(const bf16x8*)(h + (size_t)irow * EMB + ks * 32 + quad * 8);

    const f32x4 zero4 = {0.f, 0.f, 0.f, 0.f};
    f32x4 acc[4];
    #pragma unroll
    for (int nt = 0; nt < 4; ++nt) acc[nt] = zero4;

    #pragma unroll
    for (int c = 0; c < 8; ++c) {
        const int chunk = wave * 8 + c;
        const int row = chunk * 4 + (lane >> 4);
        const int b = (lane & 15) ^ (row & 15);
        async_cp16(GWT + (size_t)row * EMB + b * 8, &Gs[0][chunk * 1024]);
    }
    #pragma unroll 1
    for (int q = 0; q < NQ; ++q) {
        __syncthreads();   // stage(q) complete + prev compute's reads done
        if (q + 1 < NQ) {
            const unsigned short* src = GWT + (size_t)(q + 1) * (EMB * EMB);
            unsigned char* dst = Gs[(q + 1) & 1];
            #pragma unroll
            for (int c = 0; c < 8; ++c) {
                const int chunk = wave * 8 + c;
                const int row = chunk * 4 + (lane >> 4);
                const int b = (lane & 15) ^ (row & 15);
                async_cp16(src + (size_t)row * EMB + b * 8, dst + chunk * 1024);
            }
        }
        const float u = UT[(size_t)q * N_TOK + irow];
        bf16x8 au[4];
        #pragma unroll
        for (int ks = 0; ks < 4; ++ks) {
            const s16x8 raw = __builtin_bit_cast(s16x8, araw[ks]);
            u32x4 ww;
            #pragma unroll
            for (int w = 0; w < 4; ++w) {
                const float fa = bf16_to_f32((unsigned short)raw[2 * w])     * u;
                const float fb = bf16_to_f32((unsigned short)raw[2 * w + 1]) * u;
                ww[w] = pack_trunc(fa, fb);
            }
            au[ks] = __builtin_bit_cast(bf16x8, ww);
        }
        const unsigned char* gb = Gs[q & 1];
        #pragma unroll
        for (int nt = 0; nt < 4; ++nt) {
            const int o = F * 64 + nt * 16 + l15;
            #pragma unroll
            for (int ks = 0; ks < 4; ++ks) {
                const int b = (ks * 4 + quad) ^ (o & 15);
                const bf16x8 bfr = *(const bf16x8*)(gb + o * 256 + b * 16);
                acc[nt] = __builtin_amdgcn_mfma_f32_16x16x32_bf16(au[ks], bfr, acc[nt], 0, 0, 0);
            }
        }
    }

    #pragma unroll
    for (int nt = 0; nt < 4; ++nt) {
        const int o = F * 64 + nt * 16 + l15;
        const float bias = b2[o];
        #pragma unroll
        for (int r = 0; r < 4; ++r) {
            const float v = acc[nt][r] + bias;
            out[(size_t)(i0 + quad * 4 + r) * EMB + o] = v > 0.f ? v : 0.f;
        }
    }
}

extern "C" void kernel_launch(void* const* d_in, const int* in_sizes, int n_in,
                              void* d_out, int out_size, void* d_ws, size_t ws_size,
                              hipStream_t stream) {
    const float* x  = (const float*)d_in[0];
    const float* W1 = (const float*)d_in[1];
    const float* b1 = (const float*)d_in[2];
    const float* W2 = (const float*)d_in[3];
    const float* b2 = (const float*)d_in[4];
    float* out = (float*)d_out;

    char* ws = (char*)d_ws;
    // ws (bytes): h 4MB | hT 4MB | W1T 64KB | W2T 32KB | UT 832KB
    // | Gp 13x16x64KB (13.6MB) | G 832KB | GWT 416KB  ~= 24MB
    unsigned short* h   = (unsigned short*)(ws);
    unsigned short* hT  = (unsigned short*)(ws + 4194304);
    unsigned short* W1T = (unsigned short*)(ws + 8388608);
    unsigned short* W2T = (unsigned short*)(ws + 8454144);
    float*          UT  = (float*)        (ws + 8486912);
    float*          Gp  = (float*)        (ws + 9338880);
    float*          G   = (float*)        (ws + 23068672);
    unsigned short* GWT = (unsigned short*)(ws + 23920640);

    k0_transpose<<<dim3(16),      dim3(256), 0, stream>>>(W1, W2, W1T, W2T);
    k1_proj     <<<dim3(256),     dim3(256), 0, stream>>>(x, W1T, b1, h, hT, UT);
    k2a_gram    <<<dim3(NQ * KC), dim3(256), 0, stream>>>(hT, UT, Gp);
    k2r_reduce  <<<dim3(NQ * 64), dim3(256), 0, stream>>>(Gp, G);
    k2b_gwt     <<<dim3(NQ * 8),  dim3(256), 0, stream>>>(G, W2T, GWT);
    k2c_apply   <<<dim3(512),     dim3(256), 0, stream>>>(h, GWT, UT, b2, out);
}